// Round 18
// baseline (130.847 us; speedup 1.0000x reference)
//
#include <hip/hip_runtime.h>

typedef __attribute__((ext_vector_type(8))) short bf16x8;
typedef __attribute__((ext_vector_type(4))) float f32x4;
typedef __attribute__((ext_vector_type(4))) short short4v;
typedef __attribute__((ext_vector_type(4))) unsigned int u32x4;
typedef __attribute__((ext_vector_type(2))) unsigned int u32x2;

#define DEVFN static __device__ __forceinline__

DEVFN short f2bf(float f) {
  unsigned int u = __builtin_bit_cast(unsigned int, f);
  unsigned int r = (u + 0x7FFFu + ((u >> 16) & 1u)) >> 16;   // RNE
  return (short)r;
}

DEVFN unsigned int pack2bf(float a, float b) {
  unsigned int lo = (unsigned int)(unsigned short)f2bf(a);
  unsigned int hi = (unsigned int)(unsigned short)f2bf(b);
  return lo | (hi << 16);
}

DEVFN f32x4 mfma_bf16(bf16x8 a, bf16x8 b, f32x4 c) {
  return __builtin_amdgcn_mfma_f32_16x16x32_bf16(a, b, c, 0, 0, 0);
}

DEVFN f32x4 zero4() { f32x4 z = {0.f, 0.f, 0.f, 0.f}; return z; }
DEVFN bf16x8 zero8() { bf16x8 z = {0,0,0,0,0,0,0,0}; return z; }

DEVFN void gload_lds16(const void* g, void* l) {
  __builtin_amdgcn_global_load_lds(
      (const __attribute__((address_space(1))) unsigned int*)g,
      (__attribute__((address_space(3))) unsigned int*)l, 16, 0, 0);
}

DEVFN bf16x8 lds8(const short* p) {
  short4v lo = *reinterpret_cast<const short4v*>(p);
  short4v hi = *reinterpret_cast<const short4v*>(p + 4);
  bf16x8 r;
  r[0] = lo[0]; r[1] = lo[1]; r[2] = lo[2]; r[3] = lo[3];
  r[4] = hi[0]; r[5] = hi[1]; r[6] = hi[2]; r[7] = hi[3];
  return r;
}

DEVFN bf16x8 cvt8v(float4 u0, float4 u1) {
  bf16x8 r;
  r[0] = f2bf(u0.x); r[1] = f2bf(u0.y); r[2] = f2bf(u0.z); r[3] = f2bf(u0.w);
  r[4] = f2bf(u1.x); r[5] = f2bf(u1.y); r[6] = f2bf(u1.z); r[7] = f2bf(u1.w);
  return r;
}

DEVFN float bfhi2f(unsigned int hi16) {
  return __builtin_bit_cast(float, hi16 << 16);
}
DEVFN float bfhi2f_hi(unsigned int word) {
  return __builtin_bit_cast(float, word & 0xffff0000u);
}

// ---------------------------------------------------------------------------
// Weight pack: fold BN scale, cvt bf16, fragment-major layout
// ---------------------------------------------------------------------------
__global__ void pack_w_k(const float* __restrict__ w, const float* __restrict__ g,
                         const float* __restrict__ b, const float* __restrict__ m,
                         const float* __restrict__ v, short* __restrict__ pk,
                         float* __restrict__ bias, int O) {
  const int t = blockIdx.x * 256 + threadIdx.x;
  const int nt = O >> 4;
  const int total = nt * 8 * 64;
  if (t < total) {
    int lane = t & 63;
    int j = (t >> 6) % nt;
    int c = (t >> 6) / nt;
    int row = j * 16 + (lane & 15);
    int col = c * 32 + (lane >> 4) * 8;
    float s = g[row] * rsqrtf(v[row] + 1e-5f);
    const float* wp = w + (size_t)row * 256 + col;
    short* o = pk + (size_t)t * 8;
#pragma unroll
    for (int e = 0; e < 8; ++e) o[e] = f2bf(wp[e] * s);
  }
  if (t < O) {
    float s = g[t] * rsqrtf(v[t] + 1e-5f);
    bias[t] = b[t] - m[t] * s;
  }
}

// ---------------------------------------------------------------------------
// Bias gather in S-fragment layout (verified R14).
// ---------------------------------------------------------------------------
__global__ void ab_gather2(const float* __restrict__ tab,
                           const int* __restrict__ idxs,
                           u32x2* __restrict__ ab3, int n_off) {
  const int blk = blockIdx.x;
  const int t = blk % 13, w = (blk / 13) & 3, h = blk / 52;
  const int lane = threadIdx.x;
  const int l15 = lane & 15, g = lane >> 4;
  int q = w * 16 + l15; if (q > 48) q = 48;
  const int nb = (t >> 1) * 32 + g * 8 + (t & 1) * 4;
  u32x2 out; out[0] = 0u; out[1] = 0u;
  if (nb < 196) {
    const int* irow = idxs + q * 196 + nb;
    const float* th = tab + h * n_off;
    out[0] = pack2bf(th[irow[0]], th[irow[1]]);
    out[1] = pack2bf(th[irow[2]], th[irow[3]]);
  }
  ab3[(size_t)blk * 64 + lane] = out;
}

// ---------------------------------------------------------------------------
// Kernel 1: kv gemm (kv5 structure, R14 body). ONE CHANGE vs R17: NO
// __launch_bounds__ — let residency be purely resource-driven (A/B test of
// the waves-per-EU-attribute-as-residency-cap hypothesis).
// grid = 1568, 512 thr.
// ---------------------------------------------------------------------------
__global__ void kv_gemm5(
    const float* __restrict__ x, const short* __restrict__ pk,
    const float* __restrict__ bias, short* __restrict__ k_out,
    short* __restrict__ vT_out) {
  __shared__ short xs2[16384];   // 64 rows x 256 bf16, swizzled, 32 KB
  const int tid = threadIdx.x, w = tid >> 6, lane = tid & 63;
  const int l15 = lane & 15, g = lane >> 4;
  const int mt = blockIdx.x;

  const float* xb = x + (size_t)mt * 64 * 256;
#pragma unroll
  for (int it = 0; it < 4; ++it) {
    int i = it * 512 + tid;
    int row = i >> 5, gc = i & 31;
    const float* src = xb + row * 256 + gc * 8;
    float4 u0 = *reinterpret_cast<const float4*>(src);
    float4 u1 = *reinterpret_cast<const float4*>(src + 4);
    *reinterpret_cast<bf16x8*>(reinterpret_cast<char*>(xs2) + row * 512 +
                               ((gc * 16) ^ ((row & 7) << 4))) = cvt8v(u0, u1);
  }
  __syncthreads();   // the ONLY barrier

  f32x4 acc[4][3];
#pragma unroll
  for (int m = 0; m < 4; ++m) {
    acc[m][0] = zero4(); acc[m][1] = zero4(); acc[m][2] = zero4();
  }
  const int swz = (l15 & 7) << 4;
#pragma unroll
  for (int c = 0; c < 8; ++c) {
    bf16x8 wf0 = *reinterpret_cast<const bf16x8*>(pk + ((size_t)(c * 24 + 3 * w) * 64 + lane) * 8);
    bf16x8 wf1 = *reinterpret_cast<const bf16x8*>(pk + ((size_t)(c * 24 + 3 * w + 1) * 64 + lane) * 8);
    bf16x8 wf2 = *reinterpret_cast<const bf16x8*>(pk + ((size_t)(c * 24 + 3 * w + 2) * 64 + lane) * 8);
#pragma unroll
    for (int m = 0; m < 4; ++m) {
      const int row = m * 16 + l15;
      bf16x8 a = *reinterpret_cast<const bf16x8*>(
          reinterpret_cast<const char*>(xs2) + row * 512 +
          ((c * 64 + g * 16) ^ swz));
      acc[m][0] = mfma_bf16(a, wf0, acc[m][0]);
      acc[m][1] = mfma_bf16(a, wf1, acc[m][1]);
      acc[m][2] = mfma_bf16(a, wf2, acc[m][2]);
    }
  }

  const float bvK = bias[(3 * w) * 16 + l15];
  const float bv1 = bias[(3 * w + 1) * 16 + l15];
  const float bv2 = bias[(3 * w + 2) * 16 + l15];
#pragma unroll
  for (int m = 0; m < 4; ++m) {
    const int row0 = mt * 64 + m * 16 + g * 4;
    const int bb_ = row0 / 196, n0 = row0 % 196;
    short* kp = k_out + ((size_t)(bb_ * 8 + w) * 196 + n0) * 16 + l15;
#pragma unroll
    for (int r = 0; r < 4; ++r) kp[r * 16] = f2bf(acc[m][0][r] + bvK);
    short4v sv;
#pragma unroll
    for (int r = 0; r < 4; ++r) sv[r] = f2bf(acc[m][1][r] + bv1);
    *reinterpret_cast<short4v*>(
        vT_out + ((size_t)(bb_ * 8 + w) * 32 + l15) * 196 + n0) = sv;
#pragma unroll
    for (int r = 0; r < 4; ++r) sv[r] = f2bf(acc[m][2][r] + bv2);
    *reinterpret_cast<short4v*>(
        vT_out + ((size_t)(bb_ * 8 + w) * 32 + 16 + l15) * 196 + n0) = sv;
  }
}

// ---------------------------------------------------------------------------
// Kernel 2: q = xs @ pk_q + bias -> bf16 (B*49, 128). grid = 392. (verified)
// ---------------------------------------------------------------------------
__global__ __launch_bounds__(256) void q_gemm2(
    const float* __restrict__ x, const short* __restrict__ pk,
    const float* __restrict__ bias, short* __restrict__ out) {
  __shared__ short bs[8 * 512];
  __shared__ float sb[128];
  const int tid = threadIdx.x, w_id = tid >> 6, lane = tid & 63;
  const int l15 = lane & 15, gq = lane >> 4;
  const int mt = blockIdx.x;
  if (tid < 128) sb[tid] = bias[tid];
  const int arow = mt * 64 + w_id * 16 + l15;
  const int b = arow / 49, qi = arow % 49;
  const int n = 28 * (qi / 7) + 2 * (qi % 7);
  const float* xrow = x + ((size_t)b * 196 + n) * 256;

  f32x4 acc[8];
#pragma unroll
  for (int j = 0; j < 8; ++j) acc[j] = zero4();

  for (int c = 0; c < 8; ++c) {
    for (int seg = w_id; seg < 8; seg += 4)
      gload_lds16(pk + ((size_t)(c * 8 + seg) * 64 + lane) * 8, &bs[seg * 512]);
    const float4 u0 = *reinterpret_cast<const float4*>(xrow + c * 32 + gq * 8);
    const float4 u1 = *reinterpret_cast<const float4*>(xrow + c * 32 + gq * 8 + 4);
    bf16x8 a = cvt8v(u0, u1);
    __syncthreads();
#pragma unroll
    for (int j = 0; j < 8; ++j) {
      bf16x8 bj = *reinterpret_cast<const bf16x8*>(&bs[(j * 64 + lane) * 8]);
      acc[j] = mfma_bf16(a, bj, acc[j]);
    }
    __syncthreads();
  }
  const int orow = mt * 64 + w_id * 16 + gq * 4;
#pragma unroll
  for (int j = 0; j < 8; ++j) {
    int ch = j * 16 + l15;
    float bb = sb[ch];
#pragma unroll
    for (int r = 0; r < 4; ++r)
      out[(size_t)(orow + r) * 128 + ch] = f2bf(acc[j][r] + bb);
  }
}

// ---------------------------------------------------------------------------
// Kernel 3: attention with K staged in LDS + coalesced S-layout bias.
// Single barrier. grid = 4096 (b,h), 256 thr. (verified R14)
// ---------------------------------------------------------------------------
__global__ __launch_bounds__(256) void attn4_k(
    const short* __restrict__ k_ws, const short* __restrict__ vT_ws,
    const short* __restrict__ qw, const u32x2* __restrict__ ab3,
    short* __restrict__ out) {
  __shared__ short vt[6304];   // V^T [32][196] packed + 64 B guard
  __shared__ short kst[3200];  // K [196][16] packed (6272 B) + guard
  const int b = blockIdx.x >> 3, h = blockIdx.x & 7;
  const int tid = threadIdx.x, w_id = tid >> 6, lane = tid & 63;
  const int l15 = lane & 15, g = lane >> 4;

  if (tid < 16) *reinterpret_cast<unsigned int*>(&vt[6272 + tid * 2]) = 0u;

  const short* vsrc = vT_ws + (size_t)(b * 8 + h) * 6272;
  for (int s = w_id; s < 13; s += 4) {
    if (s * 64 + lane < 784)
      gload_lds16(vsrc + (size_t)(s * 64 + lane) * 8, &vt[s * 512]);
  }
  const short* ksrc = k_ws + (size_t)(b * 8 + h) * 3136;
  for (int s = w_id; s < 7; s += 4) {
    if (s * 64 + lane < 392)
      gload_lds16(ksrc + (size_t)(s * 64 + lane) * 8, &kst[s * 512]);
  }

  const int q = w_id * 16 + l15;
  const bool qok = q < 49;
  bf16x8 bq = zero8();
  if (g < 2 && qok)
    bq = *reinterpret_cast<const bf16x8*>(
        qw + ((size_t)b * 49 + q) * 128 + h * 16 + g * 8);

  __syncthreads();   // drains vmcnt: K + V^T staged. The ONLY barrier.

  f32x4 s[13];
#pragma unroll
  for (int t = 0; t < 13; ++t) {
    int n_a = (t >> 1) * 32 + (l15 >> 2) * 8 + (t & 1) * 4 + (l15 & 3);
    bf16x8 ak = zero8();
    if (g < 2 && n_a < 196) ak = lds8(&kst[n_a * 16 + g * 8]);
    s[t] = mfma_bf16(ak, bq, zero4());
  }

  const u32x2* abp = ab3 + (size_t)((h * 4 + w_id) * 13) * 64 + lane;
#pragma unroll
  for (int t = 0; t < 13; ++t) {
    int nb = (t >> 1) * 32 + g * 8 + (t & 1) * 4;
    if (nb < 196) {
      u32x2 bv = abp[t * 64];
      s[t][0] = s[t][0] * 0.25f + bfhi2f(bv[0]);
      s[t][1] = s[t][1] * 0.25f + bfhi2f_hi(bv[0]);
      s[t][2] = s[t][2] * 0.25f + bfhi2f(bv[1]);
      s[t][3] = s[t][3] * 0.25f + bfhi2f_hi(bv[1]);
    } else {
      s[t][0] = -1e30f; s[t][1] = -1e30f; s[t][2] = -1e30f; s[t][3] = -1e30f;
    }
  }

  float mx = s[0][0];
#pragma unroll
  for (int t = 0; t < 13; ++t)
    mx = fmaxf(mx, fmaxf(fmaxf(s[t][0], s[t][1]), fmaxf(s[t][2], s[t][3])));
  mx = fmaxf(mx, __shfl_xor(mx, 16, 64));
  mx = fmaxf(mx, __shfl_xor(mx, 32, 64));
  float sum = 0.f;
#pragma unroll
  for (int t = 0; t < 13; ++t) {
#pragma unroll
    for (int r = 0; r < 4; ++r) {
      float e = __expf(s[t][r] - mx);
      s[t][r] = e;
      sum += e;
    }
  }
  sum += __shfl_xor(sum, 16, 64);
  sum += __shfl_xor(sum, 32, 64);
  const float inv = 1.f / sum;

  unsigned int pkr[14][2];
#pragma unroll
  for (int t = 0; t < 13; ++t) {
    pkr[t][0] = pack2bf(s[t][0] * inv, s[t][1] * inv);
    pkr[t][1] = pack2bf(s[t][2] * inv, s[t][3] * inv);
  }
  pkr[13][0] = 0u; pkr[13][1] = 0u;

  f32x4 o0 = zero4(), o1 = zero4();
#pragma unroll
  for (int c = 0; c < 7; ++c) {
    u32x4 bp_u;
    bp_u[0] = pkr[2 * c][0];     bp_u[1] = pkr[2 * c][1];
    bp_u[2] = pkr[2 * c + 1][0]; bp_u[3] = pkr[2 * c + 1][1];
    bf16x8 bp = __builtin_bit_cast(bf16x8, bp_u);
    bf16x8 a0 = lds8(&vt[l15 * 196 + c * 32 + g * 8]);
    bf16x8 a1 = lds8(&vt[(16 + l15) * 196 + c * 32 + g * 8]);
    o0 = mfma_bf16(a0, bp, o0);
    o1 = mfma_bf16(a1, bp, o1);
  }

  if (qok) {
    short* op = out + (((size_t)b * 49 + q) * 256 + h * 32 + g * 4);
    short4v v0, v1;
#pragma unroll
    for (int r = 0; r < 4; ++r) {
      float x0 = o0[r];
      v0[r] = f2bf(x0 * fminf(fmaxf(x0 + 3.f, 0.f), 6.f) * (1.f / 6.f));
      float x1 = o1[r];
      v1[r] = f2bf(x1 * fminf(fmaxf(x1 + 3.f, 0.f), 6.f) * (1.f / 6.f));
    }
    *reinterpret_cast<short4v*>(op) = v0;
    *reinterpret_cast<short4v*>(op + 16) = v1;
  }
}

// ---------------------------------------------------------------------------
// Kernel 4: streaming projection (p_gemm3, verified). grid = 1568.
// ---------------------------------------------------------------------------
__global__ void p_gemm3(
    const short* __restrict__ a_in, const short* __restrict__ pk,
    const float* __restrict__ bias, float* __restrict__ out) {
  __shared__ short as_[32 * 256];
  const int tid = threadIdx.x, w = tid >> 6, lane = tid & 63;
  const int l15 = lane & 15, g = lane >> 4;
  const int half = blockIdx.x & 1;
  const int mt = blockIdx.x >> 1;

  const short* ab_ = a_in + (size_t)mt * 32 * 256;
#pragma unroll
  for (int it = 0; it < 4; ++it) {
    int i = it * 256 + tid;
    int row = i >> 5, gc = i & 31;
    bf16x8 vv = *reinterpret_cast<const bf16x8*>(ab_ + row * 256 + gc * 8);
    *reinterpret_cast<bf16x8*>(reinterpret_cast<char*>(as_) + row * 512 +
                               ((gc * 16) ^ ((row & 7) << 4))) = vv;
  }
  __syncthreads();

  f32x4 acc[2][4];
#pragma unroll
  for (int m = 0; m < 2; ++m)
#pragma unroll
    for (int jj = 0; jj < 4; ++jj) acc[m][jj] = zero4();

  const int jbase = half * 16 + w * 4;
#pragma unroll
  for (int c = 0; c < 8; ++c) {
    bf16x8 wf[4];
#pragma unroll
    for (int jj = 0; jj < 4; ++jj)
      wf[jj] = *reinterpret_cast<const bf16x8*>(
          pk + ((size_t)(c * 32 + jbase + jj) * 64 + lane) * 8);
#pragma unroll
    for (int m = 0; m < 2; ++m) {
      const int row = m * 16 + l15;
      bf16x8 a = *reinterpret_cast<const bf16x8*>(
          reinterpret_cast<const char*>(as_) + row * 512 +
          ((c * 64 + g * 16) ^ ((row & 7) << 4)));
#pragma unroll
      for (int jj = 0; jj < 4; ++jj)
        acc[m][jj] = mfma_bf16(a, wf[jj], acc[m][jj]);
    }
  }

#pragma unroll
  for (int m = 0; m < 2; ++m) {
    const int row0 = mt * 32 + m * 16 + g * 4;
#pragma unroll
    for (int jj = 0; jj < 4; ++jj) {
      const int och = (jbase + jj) * 16 + l15;
      const float bv = bias[och];
#pragma unroll
      for (int r = 0; r < 4; ++r)
        out[(size_t)(row0 + r) * 512 + och] = acc[m][jj][r] + bv;
    }
  }
}

// ---------------------------------------------------------------------------
extern "C" void kernel_launch(void* const* d_in, const int* in_sizes, int n_in,
                              void* d_out, int out_size, void* d_ws, size_t ws_size,
                              hipStream_t stream) {
  const float* x    = (const float*)d_in[0];
  const float* w_kv = (const float*)d_in[1];
  const float* kv_g = (const float*)d_in[2];
  const float* kv_b = (const float*)d_in[3];
  const float* kv_m = (const float*)d_in[4];
  const float* kv_v = (const float*)d_in[5];
  const float* w_q  = (const float*)d_in[6];
  const float* q_g  = (const float*)d_in[7];
  const float* q_b  = (const float*)d_in[8];
  const float* q_m  = (const float*)d_in[9];
  const float* q_v  = (const float*)d_in[10];
  const float* w_p  = (const float*)d_in[11];
  const float* p_g  = (const float*)d_in[12];
  const float* p_b  = (const float*)d_in[13];
  const float* p_m  = (const float*)d_in[14];
  const float* p_v  = (const float*)d_in[15];
  const float* ab_t = (const float*)d_in[16];
  const int*   idxs = (const int*)d_in[17];
  const int n_off = in_sizes[16] / 8;

  char* ws = (char*)d_ws;
  short* pk_kv  = (short*)(ws);                    //    196,608
  short* pk_q   = (short*)(ws + 196608);           //     65,536
  short* pk_p   = (short*)(ws + 262144);           //    262,144
  float* bs_kv  = (float*)(ws + 524288);           //      1,536
  float* bs_q   = (float*)(ws + 525824);           //        512
  float* bs_p   = (float*)(ws + 526336);           //      2,048
  u32x2* ab3_ws = (u32x2*)(ws + 528384);           //    266,240
  short* k_ws   = (short*)(ws + 835712);           // 25,690,112 -> 26,525,824
  short* vT_ws  = (short*)(ws + 26525824);         // 51,380,224 -> 77,906,048
  short* q_ws   = (short*)(ws + 77906048);         //  6,422,528 -> 84,328,576
  short* at_ws  = (short*)(ws + 84328576);         // 12,845,056 -> 97,173,632

  pack_w_k<<<dim3(48), dim3(256), 0, stream>>>(w_kv, kv_g, kv_b, kv_m, kv_v, pk_kv, bs_kv, 384);
  pack_w_k<<<dim3(16), dim3(256), 0, stream>>>(w_q, q_g, q_b, q_m, q_v, pk_q, bs_q, 128);
  pack_w_k<<<dim3(64), dim3(256), 0, stream>>>(w_p, p_g, p_b, p_m, p_v, pk_p, bs_p, 512);
  ab_gather2<<<dim3(416), dim3(64), 0, stream>>>(ab_t, idxs, ab3_ws, n_off);

  kv_gemm5<<<dim3(1568), dim3(512), 0, stream>>>(x, pk_kv, bs_kv, k_ws, vT_ws);
  q_gemm2<<<dim3(392), dim3(256), 0, stream>>>(x, pk_q, bs_q, q_ws);
  attn4_k<<<dim3(4096), dim3(256), 0, stream>>>(k_ws, vT_ws, q_ws, ab3_ws, at_ws);
  p_gemm3<<<dim3(1568), dim3(256), 0, stream>>>(at_ws, pk_p, bs_p, (float*)d_out);
}

// Round 19
// 114.689 us; speedup vs baseline: 1.1409x; 1.1409x over previous
//
#include <hip/hip_runtime.h>

typedef __attribute__((ext_vector_type(8))) short bf16x8;
typedef __attribute__((ext_vector_type(4))) float f32x4;
typedef __attribute__((ext_vector_type(4))) short short4v;
typedef __attribute__((ext_vector_type(4))) unsigned int u32x4;
typedef __attribute__((ext_vector_type(2))) unsigned int u32x2;

#define DEVFN static __device__ __forceinline__

DEVFN short f2bf(float f) {
  unsigned int u = __builtin_bit_cast(unsigned int, f);
  unsigned int r = (u + 0x7FFFu + ((u >> 16) & 1u)) >> 16;   // RNE
  return (short)r;
}

DEVFN unsigned int pack2bf(float a, float b) {
  unsigned int lo = (unsigned int)(unsigned short)f2bf(a);
  unsigned int hi = (unsigned int)(unsigned short)f2bf(b);
  return lo | (hi << 16);
}

DEVFN f32x4 mfma_bf16(bf16x8 a, bf16x8 b, f32x4 c) {
  return __builtin_amdgcn_mfma_f32_16x16x32_bf16(a, b, c, 0, 0, 0);
}

DEVFN f32x4 zero4() { f32x4 z = {0.f, 0.f, 0.f, 0.f}; return z; }
DEVFN bf16x8 zero8() { bf16x8 z = {0,0,0,0,0,0,0,0}; return z; }

DEVFN void gload_lds16(const void* g, void* l) {
  __builtin_amdgcn_global_load_lds(
      (const __attribute__((address_space(1))) unsigned int*)g,
      (__attribute__((address_space(3))) unsigned int*)l, 16, 0, 0);
}

DEVFN bf16x8 lds8(const short* p) {
  short4v lo = *reinterpret_cast<const short4v*>(p);
  short4v hi = *reinterpret_cast<const short4v*>(p + 4);
  bf16x8 r;
  r[0] = lo[0]; r[1] = lo[1]; r[2] = lo[2]; r[3] = lo[3];
  r[4] = hi[0]; r[5] = hi[1]; r[6] = hi[2]; r[7] = hi[3];
  return r;
}

DEVFN bf16x8 cvt8v(float4 u0, float4 u1) {
  bf16x8 r;
  r[0] = f2bf(u0.x); r[1] = f2bf(u0.y); r[2] = f2bf(u0.z); r[3] = f2bf(u0.w);
  r[4] = f2bf(u1.x); r[5] = f2bf(u1.y); r[6] = f2bf(u1.z); r[7] = f2bf(u1.w);
  return r;
}

DEVFN float bfhi2f(unsigned int hi16) {
  return __builtin_bit_cast(float, hi16 << 16);
}
DEVFN float bfhi2f_hi(unsigned int word) {
  return __builtin_bit_cast(float, word & 0xffff0000u);
}

// ---------------------------------------------------------------------------
// Shared device body: weight pack (fold BN scale, cvt bf16, fragment-major)
// ---------------------------------------------------------------------------
DEVFN void pack_w_body(const float* __restrict__ w, const float* __restrict__ g,
                       const float* __restrict__ b, const float* __restrict__ m,
                       const float* __restrict__ v, short* __restrict__ pk,
                       float* __restrict__ bias, int O, int t) {
  const int nt = O >> 4;
  const int total = nt * 8 * 64;
  if (t < total) {
    int lane = t & 63;
    int j = (t >> 6) % nt;
    int c = (t >> 6) / nt;
    int row = j * 16 + (lane & 15);
    int col = c * 32 + (lane >> 4) * 8;
    float s = g[row] * rsqrtf(v[row] + 1e-5f);
    const float* wp = w + (size_t)row * 256 + col;
    short* o = pk + (size_t)t * 8;
#pragma unroll
    for (int e = 0; e < 8; ++e) o[e] = f2bf(wp[e] * s);
  }
  if (t < O) {
    float s = g[t] * rsqrtf(v[t] + 1e-5f);
    bias[t] = b[t] - m[t] * s;
  }
}

// ---------------------------------------------------------------------------
// Prologue: 3 weight packs + ab gather in ONE kernel. grid = 232, 256 thr.
// blocks [0,48): pack kv | [48,64): pack q | [64,128): pack p |
// [128,232): ab gather (each block = 4 of the old 64-thr gather blocks).
// ---------------------------------------------------------------------------
__global__ __launch_bounds__(256) void prologue_k(
    const float* __restrict__ w_kv, const float* __restrict__ kv_g,
    const float* __restrict__ kv_b, const float* __restrict__ kv_m,
    const float* __restrict__ kv_v, short* __restrict__ pk_kv,
    float* __restrict__ bs_kv,
    const float* __restrict__ w_q, const float* __restrict__ q_g,
    const float* __restrict__ q_b, const float* __restrict__ q_m,
    const float* __restrict__ q_v, short* __restrict__ pk_q,
    float* __restrict__ bs_q,
    const float* __restrict__ w_p, const float* __restrict__ p_g,
    const float* __restrict__ p_b, const float* __restrict__ p_m,
    const float* __restrict__ p_v, short* __restrict__ pk_p,
    float* __restrict__ bs_p,
    const float* __restrict__ tab, const int* __restrict__ idxs,
    u32x2* __restrict__ ab3, int n_off) {
  const int blk = blockIdx.x, tid = threadIdx.x;
  if (blk < 48) {
    pack_w_body(w_kv, kv_g, kv_b, kv_m, kv_v, pk_kv, bs_kv, 384, blk * 256 + tid);
  } else if (blk < 64) {
    pack_w_body(w_q, q_g, q_b, q_m, q_v, pk_q, bs_q, 128, (blk - 48) * 256 + tid);
  } else if (blk < 128) {
    pack_w_body(w_p, p_g, p_b, p_m, p_v, pk_p, bs_p, 512, (blk - 64) * 256 + tid);
  } else {
    const int vb = (blk - 128) * 4 + (tid >> 6);   // 0..415
    const int lane = tid & 63;
    if (vb < 416) {
      const int t = vb % 13, w = (vb / 13) & 3, h = vb / 52;
      const int l15 = lane & 15, g = lane >> 4;
      int q = w * 16 + l15; if (q > 48) q = 48;
      const int nb = (t >> 1) * 32 + g * 8 + (t & 1) * 4;
      u32x2 out; out[0] = 0u; out[1] = 0u;
      if (nb < 196) {
        const int* irow = idxs + q * 196 + nb;
        const float* th = tab + h * n_off;
        out[0] = pack2bf(th[irow[0]], th[irow[1]]);
        out[1] = pack2bf(th[irow[2]], th[irow[3]]);
      }
      ab3[(size_t)vb * 64 + lane] = out;
    }
  }
}

// ---------------------------------------------------------------------------
// kvq: kv_gemm5 (blocks 0..1567, verified R14 body) + q gemm (blocks
// 1568..1763, 512-thr adaptation of verified q_gemm2, M=128/block).
// grid = 1764, 512 thr.
// ---------------------------------------------------------------------------
__global__ __launch_bounds__(512, 4) void kvq_k(
    const float* __restrict__ x,
    const short* __restrict__ pk_kv, const float* __restrict__ bs_kv,
    short* __restrict__ k_out, short* __restrict__ vT_out,
    const short* __restrict__ pk_q, const float* __restrict__ bs_q,
    short* __restrict__ q_out) {
  __shared__ short smem[16640];   // kv: xs2[16384] | q: bs[4096] + sb f32[128]
  const int tid = threadIdx.x, w = tid >> 6, lane = tid & 63;
  const int l15 = lane & 15, g = lane >> 4;

  if (blockIdx.x < 1568) {
    // ================= kv body (verified kv5) =================
    short* xs2 = smem;
    const int mt = blockIdx.x;
    const float* xb = x + (size_t)mt * 64 * 256;
#pragma unroll
    for (int it = 0; it < 4; ++it) {
      int i = it * 512 + tid;
      int row = i >> 5, gc = i & 31;
      const float* src = xb + row * 256 + gc * 8;
      float4 u0 = *reinterpret_cast<const float4*>(src);
      float4 u1 = *reinterpret_cast<const float4*>(src + 4);
      *reinterpret_cast<bf16x8*>(reinterpret_cast<char*>(xs2) + row * 512 +
                                 ((gc * 16) ^ ((row & 7) << 4))) = cvt8v(u0, u1);
    }
    __syncthreads();   // the ONLY barrier

    f32x4 acc[4][3];
#pragma unroll
    for (int m = 0; m < 4; ++m) {
      acc[m][0] = zero4(); acc[m][1] = zero4(); acc[m][2] = zero4();
    }
    const int swz = (l15 & 7) << 4;
#pragma unroll
    for (int c = 0; c < 8; ++c) {
      bf16x8 wf0 = *reinterpret_cast<const bf16x8*>(pk_kv + ((size_t)(c * 24 + 3 * w) * 64 + lane) * 8);
      bf16x8 wf1 = *reinterpret_cast<const bf16x8*>(pk_kv + ((size_t)(c * 24 + 3 * w + 1) * 64 + lane) * 8);
      bf16x8 wf2 = *reinterpret_cast<const bf16x8*>(pk_kv + ((size_t)(c * 24 + 3 * w + 2) * 64 + lane) * 8);
#pragma unroll
      for (int m = 0; m < 4; ++m) {
        const int row = m * 16 + l15;
        bf16x8 a = *reinterpret_cast<const bf16x8*>(
            reinterpret_cast<const char*>(xs2) + row * 512 +
            ((c * 64 + g * 16) ^ swz));
        acc[m][0] = mfma_bf16(a, wf0, acc[m][0]);
        acc[m][1] = mfma_bf16(a, wf1, acc[m][1]);
        acc[m][2] = mfma_bf16(a, wf2, acc[m][2]);
      }
    }

    const float bvK = bs_kv[(3 * w) * 16 + l15];
    const float bv1 = bs_kv[(3 * w + 1) * 16 + l15];
    const float bv2 = bs_kv[(3 * w + 2) * 16 + l15];
#pragma unroll
    for (int m = 0; m < 4; ++m) {
      const int row0 = mt * 64 + m * 16 + g * 4;
      const int bb_ = row0 / 196, n0 = row0 % 196;
      short* kp = k_out + ((size_t)(bb_ * 8 + w) * 196 + n0) * 16 + l15;
#pragma unroll
      for (int r = 0; r < 4; ++r) kp[r * 16] = f2bf(acc[m][0][r] + bvK);
      short4v sv;
#pragma unroll
      for (int r = 0; r < 4; ++r) sv[r] = f2bf(acc[m][1][r] + bv1);
      *reinterpret_cast<short4v*>(
          vT_out + ((size_t)(bb_ * 8 + w) * 32 + l15) * 196 + n0) = sv;
#pragma unroll
      for (int r = 0; r < 4; ++r) sv[r] = f2bf(acc[m][2][r] + bv2);
      *reinterpret_cast<short4v*>(
          vT_out + ((size_t)(bb_ * 8 + w) * 32 + 16 + l15) * 196 + n0) = sv;
    }
  } else {
    // ================= q body (512-thr q_gemm2) =================
    short* bs = smem;                        // 8*512 shorts
    float* sb = reinterpret_cast<float*>(smem + 4096);   // 128 floats
    const int mt = blockIdx.x - 1568;        // 0..195, M=128 rows
    if (tid < 128) sb[tid] = bs_q[tid];
    const int arow = mt * 128 + w * 16 + l15;
    const int b = arow / 49, qi = arow % 49;
    const int n = 28 * (qi / 7) + 2 * (qi % 7);
    const float* xrow = x + ((size_t)b * 196 + n) * 256;

    f32x4 acc[8];
#pragma unroll
    for (int j = 0; j < 8; ++j) acc[j] = zero4();

    for (int c = 0; c < 8; ++c) {
      // 8 segs, one per wave
      gload_lds16(pk_q + ((size_t)(c * 8 + w) * 64 + lane) * 8, &bs[w * 512]);
      const float4 u0 = *reinterpret_cast<const float4*>(xrow + c * 32 + g * 8);
      const float4 u1 = *reinterpret_cast<const float4*>(xrow + c * 32 + g * 8 + 4);
      bf16x8 a = cvt8v(u0, u1);
      __syncthreads();
#pragma unroll
      for (int j = 0; j < 8; ++j) {
        bf16x8 bj = *reinterpret_cast<const bf16x8*>(&bs[(j * 64 + lane) * 8]);
        acc[j] = mfma_bf16(a, bj, acc[j]);
      }
      __syncthreads();
    }
    const int orow = mt * 128 + w * 16 + g * 4;
#pragma unroll
    for (int j = 0; j < 8; ++j) {
      int ch = j * 16 + l15;
      float bb = sb[ch];
#pragma unroll
      for (int r = 0; r < 4; ++r)
        q_out[(size_t)(orow + r) * 128 + ch] = f2bf(acc[j][r] + bb);
    }
  }
}

// ---------------------------------------------------------------------------
// attention with K staged in LDS + coalesced S-layout bias. Single barrier.
// grid = 4096 (b,h), 256 thr. (verified R14)
// ---------------------------------------------------------------------------
__global__ __launch_bounds__(256) void attn4_k(
    const short* __restrict__ k_ws, const short* __restrict__ vT_ws,
    const short* __restrict__ qw, const u32x2* __restrict__ ab3,
    short* __restrict__ out) {
  __shared__ short vt[6304];   // V^T [32][196] packed + 64 B guard
  __shared__ short kst[3200];  // K [196][16] packed (6272 B) + guard
  const int b = blockIdx.x >> 3, h = blockIdx.x & 7;
  const int tid = threadIdx.x, w_id = tid >> 6, lane = tid & 63;
  const int l15 = lane & 15, g = lane >> 4;

  if (tid < 16) *reinterpret_cast<unsigned int*>(&vt[6272 + tid * 2]) = 0u;

  const short* vsrc = vT_ws + (size_t)(b * 8 + h) * 6272;
  for (int s = w_id; s < 13; s += 4) {
    if (s * 64 + lane < 784)
      gload_lds16(vsrc + (size_t)(s * 64 + lane) * 8, &vt[s * 512]);
  }
  const short* ksrc = k_ws + (size_t)(b * 8 + h) * 3136;
  for (int s = w_id; s < 7; s += 4) {
    if (s * 64 + lane < 392)
      gload_lds16(ksrc + (size_t)(s * 64 + lane) * 8, &kst[s * 512]);
  }

  const int q = w_id * 16 + l15;
  const bool qok = q < 49;
  bf16x8 bq = zero8();
  if (g < 2 && qok)
    bq = *reinterpret_cast<const bf16x8*>(
        qw + ((size_t)b * 49 + q) * 128 + h * 16 + g * 8);

  __syncthreads();   // drains vmcnt: K + V^T staged. The ONLY barrier.

  f32x4 s[13];
#pragma unroll
  for (int t = 0; t < 13; ++t) {
    int n_a = (t >> 1) * 32 + (l15 >> 2) * 8 + (t & 1) * 4 + (l15 & 3);
    bf16x8 ak = zero8();
    if (g < 2 && n_a < 196) ak = lds8(&kst[n_a * 16 + g * 8]);
    s[t] = mfma_bf16(ak, bq, zero4());
  }

  const u32x2* abp = ab3 + (size_t)((h * 4 + w_id) * 13) * 64 + lane;
#pragma unroll
  for (int t = 0; t < 13; ++t) {
    int nb = (t >> 1) * 32 + g * 8 + (t & 1) * 4;
    if (nb < 196) {
      u32x2 bv = abp[t * 64];
      s[t][0] = s[t][0] * 0.25f + bfhi2f(bv[0]);
      s[t][1] = s[t][1] * 0.25f + bfhi2f_hi(bv[0]);
      s[t][2] = s[t][2] * 0.25f + bfhi2f(bv[1]);
      s[t][3] = s[t][3] * 0.25f + bfhi2f_hi(bv[1]);
    } else {
      s[t][0] = -1e30f; s[t][1] = -1e30f; s[t][2] = -1e30f; s[t][3] = -1e30f;
    }
  }

  float mx = s[0][0];
#pragma unroll
  for (int t = 0; t < 13; ++t)
    mx = fmaxf(mx, fmaxf(fmaxf(s[t][0], s[t][1]), fmaxf(s[t][2], s[t][3])));
  mx = fmaxf(mx, __shfl_xor(mx, 16, 64));
  mx = fmaxf(mx, __shfl_xor(mx, 32, 64));
  float sum = 0.f;
#pragma unroll
  for (int t = 0; t < 13; ++t) {
#pragma unroll
    for (int r = 0; r < 4; ++r) {
      float e = __expf(s[t][r] - mx);
      s[t][r] = e;
      sum += e;
    }
  }
  sum += __shfl_xor(sum, 16, 64);
  sum += __shfl_xor(sum, 32, 64);
  const float inv = 1.f / sum;

  unsigned int pkr[14][2];
#pragma unroll
  for (int t = 0; t < 13; ++t) {
    pkr[t][0] = pack2bf(s[t][0] * inv, s[t][1] * inv);
    pkr[t][1] = pack2bf(s[t][2] * inv, s[t][3] * inv);
  }
  pkr[13][0] = 0u; pkr[13][1] = 0u;

  f32x4 o0 = zero4(), o1 = zero4();
#pragma unroll
  for (int c = 0; c < 7; ++c) {
    u32x4 bp_u;
    bp_u[0] = pkr[2 * c][0];     bp_u[1] = pkr[2 * c][1];
    bp_u[2] = pkr[2 * c + 1][0]; bp_u[3] = pkr[2 * c + 1][1];
    bf16x8 bp = __builtin_bit_cast(bf16x8, bp_u);
    bf16x8 a0 = lds8(&vt[l15 * 196 + c * 32 + g * 8]);
    bf16x8 a1 = lds8(&vt[(16 + l15) * 196 + c * 32 + g * 8]);
    o0 = mfma_bf16(a0, bp, o0);
    o1 = mfma_bf16(a1, bp, o1);
  }

  if (qok) {
    short* op = out + (((size_t)b * 49 + q) * 256 + h * 32 + g * 4);
    short4v v0, v1;
#pragma unroll
    for (int r = 0; r < 4; ++r) {
      float x0 = o0[r];
      v0[r] = f2bf(x0 * fminf(fmaxf(x0 + 3.f, 0.f), 6.f) * (1.f / 6.f));
      float x1 = o1[r];
      v1[r] = f2bf(x1 * fminf(fmaxf(x1 + 3.f, 0.f), 6.f) * (1.f / 6.f));
    }
    *reinterpret_cast<short4v*>(op) = v0;
    *reinterpret_cast<short4v*>(op + 16) = v1;
  }
}

// ---------------------------------------------------------------------------
// streaming projection (p_gemm3, verified). grid = 1568.
// ---------------------------------------------------------------------------
__global__ void p_gemm3(
    const short* __restrict__ a_in, const short* __restrict__ pk,
    const float* __restrict__ bias, float* __restrict__ out) {
  __shared__ short as_[32 * 256];
  const int tid = threadIdx.x, w = tid >> 6, lane = tid & 63;
  const int l15 = lane & 15, g = lane >> 4;
  const int half = blockIdx.x & 1;
  const int mt = blockIdx.x >> 1;

  const short* ab_ = a_in + (size_t)mt * 32 * 256;
#pragma unroll
  for (int it = 0; it < 4; ++it) {
    int i = it * 256 + tid;
    int row = i >> 5, gc = i & 31;
    bf16x8 vv = *reinterpret_cast<const bf16x8*>(ab_ + row * 256 + gc * 8);
    *reinterpret_cast<bf16x8*>(reinterpret_cast<char*>(as_) + row * 512 +
                               ((gc * 16) ^ ((row & 7) << 4))) = vv;
  }
  __syncthreads();

  f32x4 acc[2][4];
#pragma unroll
  for (int m = 0; m < 2; ++m)
#pragma unroll
    for (int jj = 0; jj < 4; ++jj) acc[m][jj] = zero4();

  const int jbase = half * 16 + w * 4;
#pragma unroll
  for (int c = 0; c < 8; ++c) {
    bf16x8 wf[4];
#pragma unroll
    for (int jj = 0; jj < 4; ++jj)
      wf[jj] = *reinterpret_cast<const bf16x8*>(
          pk + ((size_t)(c * 32 + jbase + jj) * 64 + lane) * 8);
#pragma unroll
    for (int m = 0; m < 2; ++m) {
      const int row = m * 16 + l15;
      bf16x8 a = *reinterpret_cast<const bf16x8*>(
          reinterpret_cast<const char*>(as_) + row * 512 +
          ((c * 64 + g * 16) ^ ((row & 7) << 4)));
#pragma unroll
      for (int jj = 0; jj < 4; ++jj)
        acc[m][jj] = mfma_bf16(a, wf[jj], acc[m][jj]);
    }
  }

#pragma unroll
  for (int m = 0; m < 2; ++m) {
    const int row0 = mt * 32 + m * 16 + g * 4;
#pragma unroll
    for (int jj = 0; jj < 4; ++jj) {
      const int och = (jbase + jj) * 16 + l15;
      const float bv = bias[och];
#pragma unroll
      for (int r = 0; r < 4; ++r)
        out[(size_t)(row0 + r) * 512 + och] = acc[m][jj][r] + bv;
    }
  }
}

// ---------------------------------------------------------------------------
extern "C" void kernel_launch(void* const* d_in, const int* in_sizes, int n_in,
                              void* d_out, int out_size, void* d_ws, size_t ws_size,
                              hipStream_t stream) {
  const float* x    = (const float*)d_in[0];
  const float* w_kv = (const float*)d_in[1];
  const float* kv_g = (const float*)d_in[2];
  const float* kv_b = (const float*)d_in[3];
  const float* kv_m = (const float*)d_in[4];
  const float* kv_v = (const float*)d_in[5];
  const float* w_q  = (const float*)d_in[6];
  const float* q_g  = (const float*)d_in[7];
  const float* q_b  = (const float*)d_in[8];
  const float* q_m  = (const float*)d_in[9];
  const float* q_v  = (const float*)d_in[10];
  const float* w_p  = (const float*)d_in[11];
  const float* p_g  = (const float*)d_in[12];
  const float* p_b  = (const float*)d_in[13];
  const float* p_m  = (const float*)d_in[14];
  const float* p_v  = (const float*)d_in[15];
  const float* ab_t = (const float*)d_in[16];
  const int*   idxs = (const int*)d_in[17];
  const int n_off = in_sizes[16] / 8;

  char* ws = (char*)d_ws;
  short* pk_kv  = (short*)(ws);                    //    196,608
  short* pk_q   = (short*)(ws + 196608);           //     65,536
  short* pk_p   = (short*)(ws + 262144);           //    262,144
  float* bs_kv  = (float*)(ws + 524288);           //      1,536
  float* bs_q   = (float*)(ws + 525824);           //        512
  float* bs_p   = (float*)(ws + 526336);           //      2,048
  u32x2* ab3_ws = (u32x2*)(ws + 528384);           //    266,240
  short* k_ws   = (short*)(ws + 835712);           // 25,690,112 -> 26,525,824
  short* vT_ws  = (short*)(ws + 26525824);         // 51,380,224 -> 77,906,048
  short* q_ws   = (short*)(ws + 77906048);         //  6,422,528 -> 84,328,576
  short* at_ws  = (short*)(ws + 84328576);         // 12,845,056 -> 97,173,632

  prologue_k<<<dim3(232), dim3(256), 0, stream>>>(
      w_kv, kv_g, kv_b, kv_m, kv_v, pk_kv, bs_kv,
      w_q, q_g, q_b, q_m, q_v, pk_q, bs_q,
      w_p, p_g, p_b, p_m, p_v, pk_p, bs_p,
      ab_t, idxs, ab3_ws, n_off);

  kvq_k<<<dim3(1764), dim3(512), 0, stream>>>(
      x, pk_kv, bs_kv, k_ws, vT_ws, pk_q, bs_q, q_ws);
  attn4_k<<<dim3(4096), dim3(256), 0, stream>>>(k_ws, vT_ws, q_ws, ab3_ws, at_ws);
  p_gemm3<<<dim3(1568), dim3(256), 0, stream>>>(at_ws, pk_p, bs_p, (float*)d_out);
}